// Round 1
// baseline (3828.025 us; speedup 1.0000x reference)
//
#include <hip/hip_runtime.h>
#include <hip/hip_fp16.h>
#include <math.h>

#define B_ 32
#define S_ 1024
#define D_ 768
#define L_ 12
#define SD 786432LL      // S_*D_ halves per batch
#define SS 1048576LL     // S_*S_ halves per batch
#define DD 589824LL      // D_*D_
#define LDL 1769472LL    // 3*DD halves per layer of Wcat (2304 x 768)

typedef _Float16 half8 __attribute__((ext_vector_type(8)));
typedef float f32x4 __attribute__((ext_vector_type(4)));
typedef unsigned short u16;

// chunk swizzle for the old att epilogue LDS bounce (8-fp16 chunks in a 64-wide row)
#define SW(lr) ((((lr) ^ ((lr) >> 3)) & 7))

// ===========================================================================
// Fused QKV projection, 256x256 tile, 8 waves, deep-pipelined.
//   - K in 24 slices of BK=32, 4-slot LDS ring (A 4x16KB + B 4x16KB = 128KB)
//   - staging runs 2 slices ahead (global_load_lds w=16), counted vmcnt(4),
//     ONE barrier per slice (fused "s_waitcnt vmcnt(N); s_barrier" asm)
//   - two 16-MFMA clusters per slice wrapped in s_setprio(1/0)
//   - staging swizzle: chunk c = kc ^ ((row>>1)&3)  -> 2-way (free) ds_read
//   - epilogue C-tile swizzle key (row&7)^((row>>3)&7): conflict-free row
//     half8 reads (Q/K) and <=4-way column u16 reads (V transpose)
//   - XCD m-slab mapping kept: per-XCD set = rolling A panel + Wcat in L2
// ===========================================================================
template<int SWIZ>
__global__ __launch_bounds__(512, 2)
void gemm_qkv2_k(const __half* __restrict__ A, const __half* __restrict__ Wt,
                 const float* __restrict__ biasC, const float* __restrict__ scaleC,
                 float aBias,
                 __half* __restrict__ CQ, __half* __restrict__ CK, __half* __restrict__ CVt,
                 int nBase, int tilesX, int mPerXcd)
{
    __shared__ __align__(16) u16 smem[65536];    // 128 KB
    const int K = 768;

    int mIdx, nxI;
    if (SWIZ) {
        const int flat = blockIdx.x;
        const int xcd = flat & 7;
        const int jj = flat >> 3;
        const int mLocal = jj / tilesX;
        nxI = jj - mLocal * tilesX;
        mIdx = xcd * mPerXcd + mLocal;
    } else {
        mIdx = blockIdx.x / tilesX;
        nxI = blockIdx.x - mIdx * tilesX;
    }
    const int m0 = mIdx * 256;
    const int n0 = nxI * 256;

    const int t = threadIdx.x;
    const int l = t & 63, w = t >> 6;
    const int wr = w & 1, wc = w >> 1;          // 2 M-waves x 4 N-waves
    const int q = l >> 4, lr = l & 15;

    // ---- staging: thread covers linear 16B chunks pA0 = t and pA1 = t+512
    // LDS chunk (r, c) holds global (r, kc) with c = kc ^ ((r>>1)&3)
    const int pA0 = t, pA1 = t + 512;
    const int rA0 = pA0 >> 2, rA1 = pA1 >> 2;
    const int kA0 = (pA0 & 3) ^ ((rA0 >> 1) & 3);
    const int kA1 = (pA1 & 3) ^ ((rA1 >> 1) & 3);
    const __half* gA0 = A + (long long)(m0 + rA0) * K + kA0 * 8;
    const __half* gA1 = A + (long long)(m0 + rA1) * K + kA1 * 8;
    const __half* gB0 = Wt + (long long)(n0 + rA0) * K + kA0 * 8;
    const __half* gB1 = Wt + (long long)(n0 + rA1) * K + kA1 * 8;

    // ---- ds_read offsets (u16 units) inside one 16KB slice slot
    int aoff[2][4], boff[4];
    #pragma unroll
    for (int mh = 0; mh < 2; ++mh)
        #pragma unroll
        for (int mt = 0; mt < 4; ++mt) {
            int r = wr * 128 + mh * 64 + mt * 16 + lr;
            aoff[mh][mt] = (r * 4 + (q ^ ((r >> 1) & 3))) * 8;
        }
    #pragma unroll
    for (int nt = 0; nt < 4; ++nt) {
        int r = wc * 64 + nt * 16 + lr;
        boff[nt] = (r * 4 + (q ^ ((r >> 1) & 3))) * 8;
    }

    f32x4 acc[8][4];
    #pragma unroll
    for (int i = 0; i < 8; ++i)
        #pragma unroll
        for (int j = 0; j < 4; ++j)
            acc[i][j] = (f32x4){0.f, 0.f, 0.f, 0.f};

#define GLD(srcp, dstoff) \
    __builtin_amdgcn_global_load_lds((const __attribute__((address_space(1))) void*)(srcp), \
        (__attribute__((address_space(3))) void*)&smem[dstoff], 16, 0, 0)
#define STAGE_A(d2, s2) do { GLD(gA0 + (s2) * 32, (d2) * 8192 + pA0 * 8); \
                             GLD(gA1 + (s2) * 32, (d2) * 8192 + pA1 * 8); } while (0)
#define STAGE_B(d2, s2) do { GLD(gB0 + (s2) * 32, 32768 + (d2) * 8192 + pA0 * 8); \
                             GLD(gB1 + (s2) * 32, 32768 + (d2) * 8192 + pA1 * 8); } while (0)

    // prologue: slices 0,1 in flight (8 loads/thread)
    STAGE_A(0, 0); STAGE_B(0, 0);
    STAGE_A(1, 1); STAGE_B(1, 1);

    for (int sB = 0; sB < 24; sB += 4) {
        #pragma unroll
        for (int j = 0; j < 4; ++j) {
            const int s = sB + j;
            // boundary: slice s's 4 loads done; slice s+1's 4 stay in flight.
            // fused wait+barrier so no ds_read can slip between them.
            if (s < 23) asm volatile("s_waitcnt vmcnt(4)\n\ts_barrier" ::: "memory");
            else        asm volatile("s_waitcnt vmcnt(0)\n\ts_barrier" ::: "memory");

            const int sa = j * 8192, sb = 32768 + j * 8192;
            const int d2 = (j + 2) & 3;

            // ---- phase A: stage A(s+2), read B + A(mh=0), 16 MFMA
            if (s + 2 < 24) STAGE_A(d2, s + 2);
            half8 bf[4], af[4];
            #pragma unroll
            for (int nt = 0; nt < 4; ++nt)
                bf[nt] = *(const half8*)(const void*)&smem[sb + boff[nt]];
            #pragma unroll
            for (int mt = 0; mt < 4; ++mt)
                af[mt] = *(const half8*)(const void*)&smem[sa + aoff[0][mt]];
            __builtin_amdgcn_s_setprio(1);
            #pragma unroll
            for (int nt = 0; nt < 4; ++nt)
                #pragma unroll
                for (int mt = 0; mt < 4; ++mt)
                    acc[mt][nt] = __builtin_amdgcn_mfma_f32_16x16x32_f16(af[mt], bf[nt], acc[mt][nt], 0, 0, 0);
            __builtin_amdgcn_s_setprio(0);

            // ---- phase B: stage B(s+2), read A(mh=1), 16 MFMA
            if (s + 2 < 24) STAGE_B(d2, s + 2);
            half8 af2[4];
            #pragma unroll
            for (int mt = 0; mt < 4; ++mt)
                af2[mt] = *(const half8*)(const void*)&smem[sa + aoff[1][mt]];
            __builtin_amdgcn_s_setprio(1);
            #pragma unroll
            for (int nt = 0; nt < 4; ++nt)
                #pragma unroll
                for (int mt = 0; mt < 4; ++mt)
                    acc[4 + mt][nt] = __builtin_amdgcn_mfma_f32_16x16x32_f16(af2[mt], bf[nt], acc[4 + mt][nt], 0, 0, 0);
            __builtin_amdgcn_s_setprio(0);
        }
    }
#undef STAGE_A
#undef STAGE_B
#undef GLD

    __syncthreads();          // full drain; LDS now reused for the C tile

    const int nCat0 = n0 + nBase;
    const int region = nCat0 / 768;
    const int colBase = nCat0 - region * 768;

    float badd[4], bmul[4];
    #pragma unroll
    for (int nt = 0; nt < 4; ++nt) {
        int gn = nCat0 + wc * 64 + nt * 16 + lr;
        badd[nt] = aBias * biasC[gn];
        bmul[nt] = scaleC[gn];
    }

    // acc -> swizzled 256x256 C tile in LDS
    #pragma unroll
    for (int mh = 0; mh < 2; ++mh)
        #pragma unroll
        for (int mt = 0; mt < 4; ++mt)
            #pragma unroll
            for (int nt = 0; nt < 4; ++nt)
                #pragma unroll
                for (int i = 0; i < 4; ++i) {
                    int lrow = wr * 128 + mh * 64 + mt * 16 + q * 4 + i;
                    int lcol = wc * 64 + nt * 16 + lr;
                    float v = (acc[mh * 4 + mt][nt][i] + badd[nt]) * bmul[nt];
                    int kk = (lrow & 7) ^ ((lrow >> 3) & 7);
                    smem[lrow * 256 + (((lcol >> 3) ^ kk) << 3) + (lcol & 7)] =
                        __half_as_ushort(__float2half(v));
                }
    __syncthreads();

    if (region < 2) {
        __half* Creg = region ? CK : CQ;
        #pragma unroll
        for (int p = 0; p < 16; ++p) {
            int u = t + p * 512;
            int row = u >> 5, c = u & 31;
            int kk = (row & 7) ^ ((row >> 3) & 7);
            half8 val = *(const half8*)(const void*)&smem[row * 256 + ((c ^ kk) << 3)];
            *(half8*)(void*)&Creg[(long long)(m0 + row) * 768 + colBase + c * 8] = val;
        }
    } else {
        long long b = m0 >> 10;
        #pragma unroll
        for (int p = 0; p < 16; ++p) {
            int u = t + p * 512;
            int ncol = u >> 5, m8 = u & 31;
            __align__(16) u16 tmp[8];
            #pragma unroll
            for (int jj2 = 0; jj2 < 8; ++jj2) {
                int row = m8 * 8 + jj2;
                int kk = (row & 7) ^ ((row >> 3) & 7);
                tmp[jj2] = smem[row * 256 + ((((ncol >> 3) ^ kk)) << 3) + (ncol & 7)];
            }
            __half* dst = CVt + b * SD + (long long)(colBase + ncol) * 1024 + (m0 & 1023) + m8 * 8;
            *(half8*)(void*)dst = *(const half8*)(const void*)tmp;
        }
    }
}

// ===========================================================================
// Attention GEMM (unchanged this round): C = f(A[1024 x K] . B[N x K]^T).
// MODE 1 (QK^T): v = exp(acc*aAcc), stores fp16 P + per-(row,coltile) partial
//                sums to rsp (no-max softmax; scores bounded ~|1.2|).
// MODE 2 (PV):   v = acc * aAcc * invsum[row]  (applies 1/rowsum).
// ===========================================================================
template<int SWIZ, int MODE>
__global__ __launch_bounds__(256, 2)
void gemm_att_k(const __half* __restrict__ A, const __half* __restrict__ B,
                float aAcc, __half* __restrict__ C, int K, int ldc,
                long long sA, long long sB, long long sC,
                int tilesX, int tilesPB, int bpx,
                float* __restrict__ rsp, const float* __restrict__ invsum)
{
    __shared__ __align__(16) u16 smem[16384];
    __shared__ float sums[128 * 17];

    int nxI, ny;
    long long bz;
    if (SWIZ) {
        int flat = blockIdx.x;
        int xcd = flat & 7;
        int j = flat >> 3;
        int bLocal = j / tilesPB;
        int tt = j - bLocal * tilesPB;
        bz = (long long)(xcd * bpx + bLocal);
        ny = tt / tilesX;
        nxI = tt - ny * tilesX;
    } else {
        nxI = blockIdx.x; ny = blockIdx.y; bz = blockIdx.z;
    }

    const int t = threadIdx.x;
    const int l = t & 63, w = t >> 6;
    const int n0 = nxI * 128;
    const int m0 = ny * 128;
    A += bz * sA; B += bz * sB; C += bz * sC;

    const int wm = (w & 1) * 64, wn = (w >> 1) * 64;

    const int u0 = t, u1 = t + 256;
    const int r0 = u0 >> 2, c0 = (u0 & 3) ^ (r0 & 3);
    const int r1 = u1 >> 2, c1 = (u1 & 3) ^ (r1 & 3);
    const __half* gA0 = A + (long long)(m0 + r0) * K + c0 * 8;
    const __half* gA1 = A + (long long)(m0 + r1) * K + c1 * 8;
    const __half* gB0 = B + (long long)(n0 + r0) * K + c0 * 8;
    const __half* gB1 = B + (long long)(n0 + r1) * K + c1 * 8;
    u16* lA0 = &smem[u0 * 8];
    u16* lA1 = &smem[u1 * 8];
    u16* lB0 = &smem[4096 + u0 * 8];
    u16* lB1 = &smem[4096 + u1 * 8];

    int aoff[4], boff[4];
    const int kc = l >> 4;
    #pragma unroll
    for (int mt = 0; mt < 4; ++mt) {
        int rr = wm + mt * 16 + (l & 15);
        aoff[mt] = (rr * 4 + (kc ^ (rr & 3))) * 8;
        int rb = wn + mt * 16 + (l & 15);
        boff[mt] = (rb * 4 + (kc ^ (rb & 3))) * 8;
    }

    f32x4 acc[4][4];
    #pragma unroll
    for (int i = 0; i < 4; ++i)
        #pragma unroll
        for (int j = 0; j < 4; ++j)
            acc[i][j] = (f32x4){0.f, 0.f, 0.f, 0.f};

    for (int k0 = 0; k0 < K; k0 += 32) {
        __builtin_amdgcn_global_load_lds((const __attribute__((address_space(1))) void*)(gA0 + k0),
                                         (__attribute__((address_space(3))) void*)lA0, 16, 0, 0);
        __builtin_amdgcn_global_load_lds((const __attribute__((address_space(1))) void*)(gA1 + k0),
                                         (__attribute__((address_space(3))) void*)lA1, 16, 0, 0);
        __builtin_amdgcn_global_load_lds((const __attribute__((address_space(1))) void*)(gB0 + k0),
                                         (__attribute__((address_space(3))) void*)lB0, 16, 0, 0);
        __builtin_amdgcn_global_load_lds((const __attribute__((address_space(1))) void*)(gB1 + k0),
                                         (__attribute__((address_space(3))) void*)lB1, 16, 0, 0);
        __syncthreads();

        half8 af[4], bf[4];
        #pragma unroll
        for (int mt = 0; mt < 4; ++mt) af[mt] = *(const half8*)(const void*)&smem[aoff[mt]];
        #pragma unroll
        for (int nt = 0; nt < 4; ++nt) bf[nt] = *(const half8*)(const void*)&smem[4096 + boff[nt]];

        #pragma unroll
        for (int nt = 0; nt < 4; ++nt)
            #pragma unroll
            for (int mt = 0; mt < 4; ++mt)
                acc[mt][nt] = __builtin_amdgcn_mfma_f32_16x16x32_f16(af[mt], bf[nt], acc[mt][nt], 0, 0, 0);
        __syncthreads();
    }

    float invr[4][4];
    if (MODE == 2) {
        #pragma unroll
        for (int mt = 0; mt < 4; ++mt)
            #pragma unroll
            for (int i = 0; i < 4; ++i)
                invr[mt][i] = invsum[bz * 1024 + m0 + wm + mt * 16 + ((l >> 4) << 2) + i];
    }

    const int qbase = w * 4096;
    #pragma unroll
    for (int mt = 0; mt < 4; ++mt) {
        #pragma unroll
        for (int nt = 0; nt < 4; ++nt) {
            #pragma unroll
            for (int i = 0; i < 4; ++i) {
                int lrow = mt * 16 + ((l >> 4) << 2) + i;
                int lcol = nt * 16 + (l & 15);
                float v;
                if (MODE == 1)      v = __expf(acc[mt][nt][i] * aAcc);
                else                v = acc[mt][nt][i] * aAcc * invr[mt][i];
                int cc = lcol >> 3, c7 = lcol & 7;
                smem[qbase + lrow * 64 + ((cc ^ SW(lrow)) << 3) + c7] =
                    __half_as_ushort(__float2half(v));
            }
        }
    }
    __syncthreads();

    #pragma unroll
    for (int p = 0; p < 8; ++p) {
        int u = t + p * 256;
        int R = u >> 4, cc = u & 15;
        int qb = ((R >> 6) + ((cc >> 3) << 1)) * 4096;
        int lr = R & 63, lcc = cc & 7;
        half8 val = *(const half8*)(const void*)&smem[qb + lr * 64 + ((lcc ^ SW(lr)) << 3)];
        *(half8*)(void*)&C[(long long)(m0 + R) * ldc + n0 + cc * 8] = val;
        if (MODE == 1) {
            float s8 = 0.f;
            #pragma unroll
            for (int j = 0; j < 8; ++j) s8 += (float)val[j];
            sums[R * 17 + cc] = s8;
        }
    }
    if (MODE == 1) {
        __syncthreads();
        if (t < 128) {
            float s = 0.f;
            #pragma unroll
            for (int c = 0; c < 16; ++c) s += sums[t * 17 + c];
            rsp[bz * 8192 + (long long)(m0 + t) * 8 + nxI] = s;
        }
    }
}

// inv[i] = 1 / sum_{c<8} rsp[i*8+c]
__global__ __launch_bounds__(256)
void rowsuminv_k(const float* __restrict__ rsp, float* __restrict__ inv, int n)
{
    int i = blockIdx.x * 256 + threadIdx.x;
    if (i < n) {
        const float* p = rsp + (long long)i * 8;
        float s = ((p[0] + p[1]) + (p[2] + p[3])) + ((p[4] + p[5]) + (p[6] + p[7]));
        inv[i] = 1.0f / s;
    }
}

// ---------------------------------------------------------------------------
__global__ __launch_bounds__(256)
void cvt32to16_k(const float* __restrict__ X, __half* __restrict__ Y)
{
    long long i = ((long long)blockIdx.x * 256 + threadIdx.x) * 4;
    float4 v = *(const float4*)&X[i];
    *(__half2*)&Y[i]     = __floats2half2_rn(v.x, v.y);
    *(__half2*)&Y[i + 2] = __floats2half2_rn(v.z, v.w);
}

// W[l][k][n] fp32 -> Wcat[l][rowOff + n][k] fp16
__global__ __launch_bounds__(256)
void wtrans_k(const float* __restrict__ W, __half* __restrict__ Wt,
              long long ldL, int rowOff)
{
    __shared__ float Ls[64][65];
    const int lyr = blockIdx.z;
    const int k0 = blockIdx.y * 64, n0 = blockIdx.x * 64;
    const float* src = W + (long long)lyr * DD;
    __half* dst = Wt + (long long)lyr * ldL;
    const int t = threadIdx.x;
    #pragma unroll
    for (int p = 0; p < 4; ++p) {
        int u = t + p * 256;
        int r = u >> 4, c4 = (u & 15) * 4;
        float4 v = *(const float4*)&src[(long long)(k0 + r) * D_ + n0 + c4];
        Ls[r][c4] = v.x; Ls[r][c4 + 1] = v.y; Ls[r][c4 + 2] = v.z; Ls[r][c4 + 3] = v.w;
    }
    __syncthreads();
    #pragma unroll
    for (int p = 0; p < 2; ++p) {
        int u = t + p * 256;
        int n = u >> 3, kc8 = (u & 7) * 8;
        __align__(16) u16 tmp[8];
        #pragma unroll
        for (int j = 0; j < 8; ++j) {
            _Float16 h = (_Float16)Ls[kc8 + j][n];
            tmp[j] = *(const u16*)&h;
        }
        *(half8*)(void*)&dst[(long long)(rowOff + n0 + n) * D_ + k0 + kc8] =
            *(const half8*)(const void*)tmp;
    }
}

// build concatenated bias/scale: [l][2304]: Q: (bq, 1) K: (bk, lk) V: (bv, lv)
__global__ __launch_bounds__(256)
void bscat_k(const float* __restrict__ bq, const float* __restrict__ bk,
             const float* __restrict__ bv, const float* __restrict__ lk,
             const float* __restrict__ lv, float* __restrict__ bsb,
             float* __restrict__ bss)
{
    int i = blockIdx.x * 256 + threadIdx.x;
    if (i >= L_ * 2304) return;
    int l = i / 2304, p = i - l * 2304;
    int r = p / 768, c = p - r * 768;
    float b, s;
    if (r == 0)      { b = bq[l * 768 + c]; s = 1.f; }
    else if (r == 1) { b = bk[l * 768 + c]; s = lk[l * 768 + c]; }
    else             { b = bv[l * 768 + c]; s = lv[l * 768 + c]; }
    bsb[i] = b; bss[i] = s;
}

// ---------------- layer-12 row-0 shortcut (fp32) ----------------
__global__ __launch_bounds__(256)
void q0_k(const __half* __restrict__ H16, const __half* __restrict__ Wcat,
          const float* __restrict__ bq, float* __restrict__ q0f, float sig)
{
    const int b = blockIdx.x;
    const int n = blockIdx.y * 256 + threadIdx.x;
    const int t = threadIdx.x;
    __shared__ __half hrow[768];
    const __half* h = H16 + (long long)b * SD;
    hrow[t] = h[t]; hrow[t + 256] = h[t + 256]; hrow[t + 512] = h[t + 512];
    __syncthreads();
    const __half* wr = Wcat + 11LL * LDL + (long long)n * 768;
    float acc = 0.f;
    for (int k = 0; k < 768; ++k) acc += (float)hrow[k] * (float)wr[k];
    q0f[b * 768 + n] = acc + sig * bq[11 * 768 + n];
}

__global__ __launch_bounds__(256)
void s0_k(const float* __restrict__ q0f, const __half* __restrict__ K16,
          float* __restrict__ s0f, int b0, float aQK)
{
    const int z = blockIdx.x;
    const int b = b0 + z;
    const int s = blockIdx.y * 256 + threadIdx.x;
    const int t = threadIdx.x;
    __shared__ float qrow[768];
    qrow[t] = q0f[b * 768 + t];
    qrow[t + 256] = q0f[b * 768 + t + 256];
    qrow[t + 512] = q0f[b * 768 + t + 512];
    __syncthreads();
    const __half* kr = K16 + (long long)z * SD + (long long)s * 768;
    float acc = 0.f;
    for (int k = 0; k < 768; ++k) acc += qrow[k] * (float)kr[k];
    s0f[b * 1024 + s] = acc * aQK;
}

__global__ __launch_bounds__(256)
void sm0_k(float* __restrict__ s0f, int b0)
{
    float* p = s0f + (long long)(b0 + blockIdx.x) * 1024;
    const int t = threadIdx.x;
    float v[4];
    float mx = -1e30f;
    #pragma unroll
    for (int j = 0; j < 4; ++j) { v[j] = p[t + 256 * j]; mx = fmaxf(mx, v[j]); }
    __shared__ float red[256];
    red[t] = mx; __syncthreads();
    for (int s = 128; s > 0; s >>= 1) { if (t < s) red[t] = fmaxf(red[t], red[t + s]); __syncthreads(); }
    mx = red[0];
    __syncthreads();
    float sum = 0.f;
    #pragma unroll
    for (int j = 0; j < 4; ++j) { v[j] = __expf(v[j] - mx); sum += v[j]; }
    red[t] = sum; __syncthreads();
    for (int s = 128; s > 0; s >>= 1) { if (t < s) red[t] += red[t + s]; __syncthreads(); }
    const float inv = 1.0f / red[0];
    __syncthreads();
    #pragma unroll
    for (int j = 0; j < 4; ++j) p[t + 256 * j] = v[j] * inv;
}

__global__ __launch_bounds__(256)
void o0_k(const float* __restrict__ p0f, const __half* __restrict__ Vt16,
          float* __restrict__ o0f, int b0, float invSig)
{
    const int z = blockIdx.x;
    const int b = b0 + z;
    const int d = blockIdx.y * 256 + threadIdx.x;
    const int t = threadIdx.x;
    __shared__ float prow[1024];
    #pragma unroll
    for (int j = 0; j < 4; ++j) prow[t + 256 * j] = p0f[b * 1024 + t + 256 * j];
    __syncthreads();
    const __half* vr = Vt16 + (long long)z * SD + (long long)d * 1024;
    float acc = 0.f;
    for (int s = 0; s < 1024; ++s) acc += prow[s] * (float)vr[s];
    o0f[b * 768 + d] = acc * invSig;
}

__global__ __launch_bounds__(256)
void headf_k(const float* __restrict__ o0f, const float* __restrict__ Wh,
             const float* __restrict__ bh, float* __restrict__ out)
{
    const int b = blockIdx.x;
    const int t = threadIdx.x;
    float s = 0.f;
    for (int d = t; d < 768; d += 256) s += o0f[b * 768 + d] * Wh[d];
    __shared__ float red[256];
    red[t] = s; __syncthreads();
    for (int k = 128; k > 0; k >>= 1) { if (t < k) red[t] += red[t + k]; __syncthreads(); }
    if (t == 0) out[b] = red[0] + bh[0];
}

// ---------------------------------------------------------------------------
extern "C" void kernel_launch(void* const* d_in, const int* in_sizes, int n_in,
                              void* d_out, int out_size, void* d_ws, size_t ws_size,
                              hipStream_t stream)
{
    const float* hs = (const float*)d_in[0];
    const float* Wq = (const float*)d_in[1];
    const float* bq = (const float*)d_in[2];
    const float* Wk = (const float*)d_in[3];
    const float* bk = (const float*)d_in[4];
    const float* Wv = (const float*)d_in[5];
    const float* bv = (const float*)d_in[6];
    const float* lk = (const float*)d_in[7];
    const float* lv = (const float*)d_in[8];
    const float* Wh = (const float*)d_in[9];
    const float* bh = (const float*)d_in[10];
    float* outp = (float*)d_out;

    // ---- workspace layout ----
    __half* H16  = (__half*)d_ws;                    // 32*SD halves
    __half* Wcat = H16 + (long long)B_ * SD;         // 12*LDL halves
    float*  bsb  = (float*)(Wcat + 12LL * LDL);      // 12*2304
    float*  bss  = bsb + 12 * 2304;
    float*  q0f  = bss + 12 * 2304;                  // 32*768
    float*  s0f  = q0f + 32 * 768;                   // 32*1024
    float*  o0f  = s0f + 32 * 1024;                  // 32*768
    float*  rsp  = o0f + 32 * 768;                   // 32*1024*8 partial rowsums
    float*  inv  = rsp + 32LL * 8192;                // 32*1024
    __half* Q16  = (__half*)(inv + 32 * 1024);

    const size_t baseBytes = (size_t)((char*)Q16 - (char*)d_ws);
    const size_t perG = ((size_t)(3 * SD) + (size_t)SS) * 2;   // ~6.8 MB
    long long avail = (long long)ws_size - (long long)baseBytes;
    int G = (avail > 0) ? (int)(avail / perG) : 1;
    if (G >= 32) G = 32; else if (G >= 16) G = 16; else if (G >= 8) G = 8;
    if (G < 1) G = 1;
    __half* K16  = Q16 + (long long)G * SD;
    __half* Vt16 = K16 + (long long)G * SD;
    __half* P16  = Vt16 + (long long)G * SD;

    // ---- converts ----
    cvt32to16_k<<<dim3((int)((B_ * SD) / 1024)), 256, 0, stream>>>(hs, H16);
    wtrans_k<<<dim3(12, 12, 12), 256, 0, stream>>>(Wq, Wcat, LDL, 0);
    wtrans_k<<<dim3(12, 12, 12), 256, 0, stream>>>(Wk, Wcat, LDL, 768);
    wtrans_k<<<dim3(12, 12, 12), 256, 0, stream>>>(Wv, Wcat, LDL, 1536);
    bscat_k<<<dim3((L_ * 2304 + 255) / 256), 256, 0, stream>>>(bq, bk, bv, lk, lv, bsb, bss);

    const float scq = 0.036084391824351615f;   // 1/sqrt(768)
    float sig = 1.f;

    // ---- layers 1..11 (full) ----
    for (int lyr = 0; lyr < L_ - 1; ++lyr) {
        const __half* W = Wcat + (long long)lyr * LDL;
        const float* bb = bsb + lyr * 2304;
        const float* ss = bss + lyr * 2304;
        const float aQK = scq / (sig * sig);

        for (int b0 = 0; b0 < B_; b0 += G) {
            const int nb = (B_ - b0 < G) ? (B_ - b0) : G;
            const __half* hg = H16 + (long long)b0 * SD;

            // fused QKV projection, 256^2 pipelined; XCD m-slab when nb even
            if ((nb & 1) == 0) {
                gemm_qkv2_k<1><<<dim3(36 * nb), 512, 0, stream>>>(
                    hg, W, bb, ss, sig, Q16, K16, Vt16, 0, 9, nb >> 1);
            } else {
                gemm_qkv2_k<0><<<dim3(36 * nb), 512, 0, stream>>>(
                    hg, W, bb, ss, sig, Q16, K16, Vt16, 0, 9, 0);
            }

            if ((nb & 7) == 0) {
                gemm_att_k<1, 1><<<dim3(nb * 64), 256, 0, stream>>>(
                    Q16, K16, aQK, P16, 768, 1024, SD, SD, SS, 8, 64, nb >> 3, rsp, nullptr);
            } else {
                gemm_att_k<0, 1><<<dim3(8, 8, nb), 256, 0, stream>>>(
                    Q16, K16, aQK, P16, 768, 1024, SD, SD, SS, 8, 64, 1, rsp, nullptr);
            }

            rowsuminv_k<<<dim3(nb * 4), 256, 0, stream>>>(rsp, inv, nb * 1024);

            if ((nb & 7) == 0) {
                gemm_att_k<1, 2><<<dim3(nb * 48), 256, 0, stream>>>(
                    P16, Vt16, 4.f, H16 + (long long)b0 * SD, 1024, 768, SS, SD, SD,
                    6, 48, nb >> 3, nullptr, inv);
            } else {
                gemm_att_k<0, 2><<<dim3(6, 8, nb), 256, 0, stream>>>(
                    P16, Vt16, 4.f, H16 + (long long)b0 * SD, 1024, 768, SS, SD, SD,
                    6, 48, 1, nullptr, inv);
            }
        }
        sig *= 4.f;
    }

    // ---- layer 12: only row 0 of the output is needed ----
    const float aQK = scq / (sig * sig);
    q0_k<<<dim3(B_, 3), 256, 0, stream>>>(H16, Wcat, bq, q0f, sig);

    for (int b0 = 0; b0 < B_; b0 += G) {
        const int nb = (B_ - b0 < G) ? (B_ - b0) : G;
        const __half* hg = H16 + (long long)b0 * SD;

        // K,V projection only (cat rows 768..2303), region split at 768
        if ((nb & 1) == 0) {
            gemm_qkv2_k<1><<<dim3(24 * nb), 512, 0, stream>>>(
                hg, Wcat + 11LL * LDL + 768LL * 768, bsb + 11 * 2304, bss + 11 * 2304,
                sig, K16 /*unused*/, K16, Vt16, 768, 6, nb >> 1);
        } else {
            gemm_qkv2_k<0><<<dim3(24 * nb), 512, 0, stream>>>(
                hg, Wcat + 11LL * LDL + 768LL * 768, bsb + 11 * 2304, bss + 11 * 2304,
                sig, K16 /*unused*/, K16, Vt16, 768, 6, 0);
        }

        s0_k<<<dim3(nb, 4), 256, 0, stream>>>(q0f, K16, s0f, b0, aQK);
        sm0_k<<<dim3(nb), 256, 0, stream>>>(s0f, b0);
        o0_k<<<dim3(nb, 3), 256, 0, stream>>>(s0f, Vt16, o0f, b0, 1.f / sig);
    }

    headf_k<<<dim3(B_), 256, 0, stream>>>(o0f, Wh, bh, outp);
}

// Round 2
// 3623.014 us; speedup vs baseline: 1.0566x; 1.0566x over previous
//
#include <hip/hip_runtime.h>
#include <hip/hip_fp16.h>
#include <math.h>

#define B_ 32
#define S_ 1024
#define D_ 768
#define L_ 12
#define SD 786432LL      // S_*D_ halves per batch
#define SS 1048576LL     // S_*S_ halves per batch
#define DD 589824LL      // D_*D_
#define LDL 1769472LL    // 3*DD halves per layer of Wcat (2304 x 768)

typedef _Float16 half8 __attribute__((ext_vector_type(8)));
typedef float f32x4 __attribute__((ext_vector_type(4)));
typedef unsigned short u16;

// chunk swizzle for the epilogue LDS bounce (8-fp16 chunks within a 64-wide row)
#define SW(lr) ((((lr) ^ ((lr) >> 3)) & 7))

// global_load_lds, width 16
#define GLD16(p, o) __builtin_amdgcn_global_load_lds( \
        (const __attribute__((address_space(1))) void*)(p), \
        (__attribute__((address_space(3))) void*)&smem[o], 16, 0, 0)

// ===========================================================================
// Fused QKV projection, 128x128 tile, 4 waves, double-buffered LDS.
// C_cat = A(M x 768) . Wcat(2304 x 768)^T; epilogue region-split Q/K/Vt.
// K-loop (T3-minimum 2-phase): read cur slot -> stage next slot -> 16 MFMA
// -> vmcnt(0) + ONE barrier. Stage latency hides under MFMA; at ds_read
// time nothing is outstanding so compiler-inserted waits are free.
// Fragment swizzle kc ^ ((r>>1)&3): conflict-free b128 reads (was 4-way).
// LDS: A slots @0/@4096, B slots @8192/@12288 (u16 units), 32 KB total.
// XCD m-slab mapping: per-XCD working set = rolling A m-tile + Wcat in L2.
// ===========================================================================
__global__ __launch_bounds__(256, 2)
void gemm_qkv_k(const __half* __restrict__ A, const __half* __restrict__ Wt,
                const float* __restrict__ biasC, const float* __restrict__ scaleC,
                float aBias,
                __half* __restrict__ CQ, __half* __restrict__ CK, __half* __restrict__ CVt,
                int nBase, int tilesX, int mPerXcd)
{
    __shared__ __align__(16) u16 smem[16384];
    const int K = 768;

    const int flat = blockIdx.x;
    const int xcd = flat & 7;
    const int jj = flat >> 3;
    const int mLocal = jj / tilesX;
    const int nxI = jj - mLocal * tilesX;
    const int n0 = nxI * 128;
    const int m0 = (xcd * mPerXcd + mLocal) * 128;

    const int t = threadIdx.x;
    const int l = t & 63, w = t >> 6;
    const int wm = (w & 1) * 64, wn = (w >> 1) * 64;

    // staging: thread covers chunks u0 = t, u1 = t+256 of a 128x32 slice.
    // LDS stays linear in u; the GLOBAL k-chunk is pre-swizzled (m173 pattern).
    const int u0 = t, u1 = t + 256;
    const int r0 = u0 >> 2, c0 = (u0 & 3) ^ ((r0 >> 1) & 3);
    const int r1 = u1 >> 2, c1 = (u1 & 3) ^ ((r1 >> 1) & 3);
    const __half* gA0 = A + (long long)(m0 + r0) * K + c0 * 8;
    const __half* gA1 = A + (long long)(m0 + r1) * K + c1 * 8;
    const __half* gB0 = Wt + (long long)(n0 + r0) * K + c0 * 8;
    const __half* gB1 = Wt + (long long)(n0 + r1) * K + c1 * 8;

    int aoff[4], boff[4];
    const int kc = l >> 4;
    #pragma unroll
    for (int mt = 0; mt < 4; ++mt) {
        int rr = wm + mt * 16 + (l & 15);
        aoff[mt] = (rr * 4 + (kc ^ ((rr >> 1) & 3))) * 8;
        int rb = wn + mt * 16 + (l & 15);
        boff[mt] = (rb * 4 + (kc ^ ((rb >> 1) & 3))) * 8;
    }

    f32x4 acc[4][4];
    #pragma unroll
    for (int i = 0; i < 4; ++i)
        #pragma unroll
        for (int j = 0; j < 4; ++j)
            acc[i][j] = (f32x4){0.f, 0.f, 0.f, 0.f};

    // prologue: stage slice 0 into slot 0
    GLD16(gA0, u0 * 8);         GLD16(gA1, u1 * 8);
    GLD16(gB0, 8192 + u0 * 8);  GLD16(gB1, 8192 + u1 * 8);
    asm volatile("s_waitcnt vmcnt(0)\n\ts_barrier" ::: "memory");

    int cur = 0;
    for (int k0 = 0; k0 < K; k0 += 32) {
        const int sa = cur * 4096, sb = 8192 + cur * 4096;
        half8 af[4], bf[4];
        #pragma unroll
        for (int mt = 0; mt < 4; ++mt) af[mt] = *(const half8*)(const void*)&smem[sa + aoff[mt]];
        #pragma unroll
        for (int nt = 0; nt < 4; ++nt) bf[nt] = *(const half8*)(const void*)&smem[sb + boff[nt]];
        __builtin_amdgcn_sched_barrier(0);
        if (k0 + 32 < K) {
            const int nsa = (cur ^ 1) * 4096, nsb = 8192 + (cur ^ 1) * 4096;
            GLD16(gA0 + k0 + 32, nsa + u0 * 8);  GLD16(gA1 + k0 + 32, nsa + u1 * 8);
            GLD16(gB0 + k0 + 32, nsb + u0 * 8);  GLD16(gB1 + k0 + 32, nsb + u1 * 8);
        }
        #pragma unroll
        for (int nt = 0; nt < 4; ++nt)
            #pragma unroll
            for (int mt = 0; mt < 4; ++mt)
                acc[mt][nt] = __builtin_amdgcn_mfma_f32_16x16x32_f16(af[mt], bf[nt], acc[mt][nt], 0, 0, 0);
        asm volatile("s_waitcnt vmcnt(0)\n\ts_barrier" ::: "memory");
        cur ^= 1;
    }

    const int nCat0 = n0 + nBase;
    const int region = nCat0 / 768;
    const int colBase = nCat0 - region * 768;

    float badd[4], bmul[4];
    #pragma unroll
    for (int nt = 0; nt < 4; ++nt) {
        int gn = nCat0 + wn + nt * 16 + (l & 15);
        badd[nt] = aBias * biasC[gn];
        bmul[nt] = scaleC[gn];
    }

    const int qbase = w * 4096;
    #pragma unroll
    for (int mt = 0; mt < 4; ++mt) {
        #pragma unroll
        for (int nt = 0; nt < 4; ++nt) {
            #pragma unroll
            for (int i = 0; i < 4; ++i) {
                int lrow = mt * 16 + ((l >> 4) << 2) + i;
                int lcol = nt * 16 + (l & 15);
                float v = (acc[mt][nt][i] + badd[nt]) * bmul[nt];
                int cc = lcol >> 3, c7 = lcol & 7;
                smem[qbase + lrow * 64 + ((cc ^ SW(lrow)) << 3) + c7] =
                    __half_as_ushort(__float2half(v));
            }
        }
    }
    __syncthreads();

    if (region < 2) {
        __half* Creg = region ? CK : CQ;
        #pragma unroll
        for (int p = 0; p < 8; ++p) {
            int u = t + p * 256;
            int R = u >> 4, cc = u & 15;
            int qb = ((R >> 6) + ((cc >> 3) << 1)) * 4096;
            int lr = R & 63, lcc = cc & 7;
            half8 val = *(const half8*)(const void*)&smem[qb + lr * 64 + ((lcc ^ SW(lr)) << 3)];
            *(half8*)(void*)&Creg[(long long)(m0 + R) * 768 + colBase + cc * 8] = val;
        }
    } else {
        #pragma unroll
        for (int p = 0; p < 8; ++p) {
            int u = t + p * 256;
            int Crow = u >> 4, mcc = u & 15;
            __align__(16) u16 tmp[8];
            #pragma unroll
            for (int j = 0; j < 8; ++j) {
                int m = mcc * 8 + j;
                int qb = ((m >> 6) + ((Crow >> 6) << 1)) * 4096;
                int lr = m & 63, lcol = Crow & 63;
                int lcc = lcol >> 3;
                tmp[j] = smem[qb + lr * 64 + ((lcc ^ SW(lr)) << 3) + (lcol & 7)];
            }
            long long b = m0 >> 10;
            __half* dst = CVt + b * SD + (long long)(colBase + Crow) * 1024 + (m0 & 1023) + mcc * 8;
            *(half8*)(void*)dst = *(const half8*)(const void*)tmp;
        }
    }
}

// ===========================================================================
// Attention GEMM: C = f(A[1024 x K] . B[N x K]^T), per-batch.
// Same double-buffered single-barrier K-loop + conflict-free swizzle.
// MODE 1 (QK^T): v = exp(acc*aAcc), stores fp16 P + per-(row,coltile) partial
//                sums to rsp (no-max softmax; scores bounded ~|1.2|).
// MODE 2 (PV):   v = acc * aAcc * invsum[row]  (applies 1/rowsum).
// SWIZ=1: batch b pinned to XCD b/bpx, matching the QKV m-slab mapping.
// ===========================================================================
template<int SWIZ, int MODE>
__global__ __launch_bounds__(256, 2)
void gemm_att_k(const __half* __restrict__ A, const __half* __restrict__ B,
                float aAcc, __half* __restrict__ C, int K, int ldc,
                long long sA, long long sB, long long sC,
                int tilesX, int tilesPB, int bpx,
                float* __restrict__ rsp, const float* __restrict__ invsum)
{
    __shared__ __align__(16) u16 smem[16384];
    __shared__ float sums[128 * 17];

    int nxI, ny;
    long long bz;
    if (SWIZ) {
        int flat = blockIdx.x;
        int xcd = flat & 7;
        int j = flat >> 3;
        int bLocal = j / tilesPB;
        int tt = j - bLocal * tilesPB;
        bz = (long long)(xcd * bpx + bLocal);
        ny = tt / tilesX;
        nxI = tt - ny * tilesX;
    } else {
        nxI = blockIdx.x; ny = blockIdx.y; bz = blockIdx.z;
    }

    const int t = threadIdx.x;
    const int l = t & 63, w = t >> 6;
    const int n0 = nxI * 128;
    const int m0 = ny * 128;
    A += bz * sA; B += bz * sB; C += bz * sC;

    const int wm = (w & 1) * 64, wn = (w >> 1) * 64;

    const int u0 = t, u1 = t + 256;
    const int r0 = u0 >> 2, c0 = (u0 & 3) ^ ((r0 >> 1) & 3);
    const int r1 = u1 >> 2, c1 = (u1 & 3) ^ ((r1 >> 1) & 3);
    const __half* gA0 = A + (long long)(m0 + r0) * K + c0 * 8;
    const __half* gA1 = A + (long long)(m0 + r1) * K + c1 * 8;
    const __half* gB0 = B + (long long)(n0 + r0) * K + c0 * 8;
    const __half* gB1 = B + (long long)(n0 + r1) * K + c1 * 8;

    int aoff[4], boff[4];
    const int kc = l >> 4;
    #pragma unroll
    for (int mt = 0; mt < 4; ++mt) {
        int rr = wm + mt * 16 + (l & 15);
        aoff[mt] = (rr * 4 + (kc ^ ((rr >> 1) & 3))) * 8;
        int rb = wn + mt * 16 + (l & 15);
        boff[mt] = (rb * 4 + (kc ^ ((rb >> 1) & 3))) * 8;
    }

    f32x4 acc[4][4];
    #pragma unroll
    for (int i = 0; i < 4; ++i)
        #pragma unroll
        for (int j = 0; j < 4; ++j)
            acc[i][j] = (f32x4){0.f, 0.f, 0.f, 0.f};

    // prologue: stage slice 0 into slot 0
    GLD16(gA0, u0 * 8);         GLD16(gA1, u1 * 8);
    GLD16(gB0, 8192 + u0 * 8);  GLD16(gB1, 8192 + u1 * 8);
    asm volatile("s_waitcnt vmcnt(0)\n\ts_barrier" ::: "memory");

    int cur = 0;
    for (int k0 = 0; k0 < K; k0 += 32) {
        const int sa = cur * 4096, sb = 8192 + cur * 4096;
        half8 af[4], bf[4];
        #pragma unroll
        for (int mt = 0; mt < 4; ++mt) af[mt] = *(const half8*)(const void*)&smem[sa + aoff[mt]];
        #pragma unroll
        for (int nt = 0; nt < 4; ++nt) bf[nt] = *(const half8*)(const void*)&smem[sb + boff[nt]];
        __builtin_amdgcn_sched_barrier(0);
        if (k0 + 32 < K) {
            const int nsa = (cur ^ 1) * 4096, nsb = 8192 + (cur ^ 1) * 4096;
            GLD16(gA0 + k0 + 32, nsa + u0 * 8);  GLD16(gA1 + k0 + 32, nsa + u1 * 8);
            GLD16(gB0 + k0 + 32, nsb + u0 * 8);  GLD16(gB1 + k0 + 32, nsb + u1 * 8);
        }
        #pragma unroll
        for (int nt = 0; nt < 4; ++nt)
            #pragma unroll
            for (int mt = 0; mt < 4; ++mt)
                acc[mt][nt] = __builtin_amdgcn_mfma_f32_16x16x32_f16(af[mt], bf[nt], acc[mt][nt], 0, 0, 0);
        asm volatile("s_waitcnt vmcnt(0)\n\ts_barrier" ::: "memory");
        cur ^= 1;
    }

    // per-thread 1/rowsum values for MODE 2 (broadcast loads, L2-hot)
    float invr[4][4];
    if (MODE == 2) {
        #pragma unroll
        for (int mt = 0; mt < 4; ++mt)
            #pragma unroll
            for (int i = 0; i < 4; ++i)
                invr[mt][i] = invsum[bz * 1024 + m0 + wm + mt * 16 + ((l >> 4) << 2) + i];
    }

    const int qbase = w * 4096;
    #pragma unroll
    for (int mt = 0; mt < 4; ++mt) {
        #pragma unroll
        for (int nt = 0; nt < 4; ++nt) {
            #pragma unroll
            for (int i = 0; i < 4; ++i) {
                int lrow = mt * 16 + ((l >> 4) << 2) + i;
                int lcol = nt * 16 + (l & 15);
                float v;
                if (MODE == 1)      v = __expf(acc[mt][nt][i] * aAcc);
                else                v = acc[mt][nt][i] * aAcc * invr[mt][i];
                int cc = lcol >> 3, c7 = lcol & 7;
                smem[qbase + lrow * 64 + ((cc ^ SW(lrow)) << 3) + c7] =
                    __half_as_ushort(__float2half(v));
            }
        }
    }
    __syncthreads();

    #pragma unroll
    for (int p = 0; p < 8; ++p) {
        int u = t + p * 256;
        int R = u >> 4, cc = u & 15;
        int qb = ((R >> 6) + ((cc >> 3) << 1)) * 4096;
        int lr = R & 63, lcc = cc & 7;
        half8 val = *(const half8*)(const void*)&smem[qb + lr * 64 + ((lcc ^ SW(lr)) << 3)];
        *(half8*)(void*)&C[(long long)(m0 + R) * ldc + n0 + cc * 8] = val;
        if (MODE == 1) {
            float s8 = 0.f;
            #pragma unroll
            for (int j = 0; j < 8; ++j) s8 += (float)val[j];
            sums[R * 17 + cc] = s8;
        }
    }
    if (MODE == 1) {
        __syncthreads();
        if (t < 128) {
            float s = 0.f;
            #pragma unroll
            for (int c = 0; c < 16; ++c) s += sums[t * 17 + c];
            rsp[bz * 8192 + (long long)(m0 + t) * 8 + nxI] = s;
        }
    }
}

// inv[i] = 1 / sum_{c<8} rsp[i*8+c]
__global__ __launch_bounds__(256)
void rowsuminv_k(const float* __restrict__ rsp, float* __restrict__ inv, int n)
{
    int i = blockIdx.x * 256 + threadIdx.x;
    if (i < n) {
        const float* p = rsp + (long long)i * 8;
        float s = ((p[0] + p[1]) + (p[2] + p[3])) + ((p[4] + p[5]) + (p[6] + p[7]));
        inv[i] = 1.0f / s;
    }
}

// ---------------------------------------------------------------------------
__global__ __launch_bounds__(256)
void cvt32to16_k(const float* __restrict__ X, __half* __restrict__ Y)
{
    long long i = ((long long)blockIdx.x * 256 + threadIdx.x) * 4;
    float4 v = *(const float4*)&X[i];
    *(__half2*)&Y[i]     = __floats2half2_rn(v.x, v.y);
    *(__half2*)&Y[i + 2] = __floats2half2_rn(v.z, v.w);
}

// W[l][k][n] fp32 -> Wcat[l][rowOff + n][k] fp16
__global__ __launch_bounds__(256)
void wtrans_k(const float* __restrict__ W, __half* __restrict__ Wt,
              long long ldL, int rowOff)
{
    __shared__ float Ls[64][65];
    const int lyr = blockIdx.z;
    const int k0 = blockIdx.y * 64, n0 = blockIdx.x * 64;
    const float* src = W + (long long)lyr * DD;
    __half* dst = Wt + (long long)lyr * ldL;
    const int t = threadIdx.x;
    #pragma unroll
    for (int p = 0; p < 4; ++p) {
        int u = t + p * 256;
        int r = u >> 4, c4 = (u & 15) * 4;
        float4 v = *(const float4*)&src[(long long)(k0 + r) * D_ + n0 + c4];
        Ls[r][c4] = v.x; Ls[r][c4 + 1] = v.y; Ls[r][c4 + 2] = v.z; Ls[r][c4 + 3] = v.w;
    }
    __syncthreads();
    #pragma unroll
    for (int p = 0; p < 2; ++p) {
        int u = t + p * 256;
        int n = u >> 3, kc8 = (u & 7) * 8;
        __align__(16) u16 tmp[8];
        #pragma unroll
        for (int j = 0; j < 8; ++j) {
            _Float16 h = (_Float16)Ls[kc8 + j][n];
            tmp[j] = *(const u16*)&h;
        }
        *(half8*)(void*)&dst[(long long)(rowOff + n0 + n) * D_ + k0 + kc8] =
            *(const half8*)(const void*)tmp;
    }
}

// build concatenated bias/scale: [l][2304]: Q: (bq, 1) K: (bk, lk) V: (bv, lv)
__global__ __launch_bounds__(256)
void bscat_k(const float* __restrict__ bq, const float* __restrict__ bk,
             const float* __restrict__ bv, const float* __restrict__ lk,
             const float* __restrict__ lv, float* __restrict__ bsb,
             float* __restrict__ bss)
{
    int i = blockIdx.x * 256 + threadIdx.x;
    if (i >= L_ * 2304) return;
    int l = i / 2304, p = i - l * 2304;
    int r = p / 768, c = p - r * 768;
    float b, s;
    if (r == 0)      { b = bq[l * 768 + c]; s = 1.f; }
    else if (r == 1) { b = bk[l * 768 + c]; s = lk[l * 768 + c]; }
    else             { b = bv[l * 768 + c]; s = lv[l * 768 + c]; }
    bsb[i] = b; bss[i] = s;
}

// ---------------- layer-12 row-0 shortcut (fp32) ----------------
__global__ __launch_bounds__(256)
void q0_k(const __half* __restrict__ H16, const __half* __restrict__ Wcat,
          const float* __restrict__ bq, float* __restrict__ q0f, float sig)
{
    const int b = blockIdx.x;
    const int n = blockIdx.y * 256 + threadIdx.x;
    const int t = threadIdx.x;
    __shared__ __half hrow[768];
    const __half* h = H16 + (long long)b * SD;
    hrow[t] = h[t]; hrow[t + 256] = h[t + 256]; hrow[t + 512] = h[t + 512];
    __syncthreads();
    const __half* wr = Wcat + 11LL * LDL + (long long)n * 768;
    float acc = 0.f;
    for (int k = 0; k < 768; ++k) acc += (float)hrow[k] * (float)wr[k];
    q0f[b * 768 + n] = acc + sig * bq[11 * 768 + n];
}

__global__ __launch_bounds__(256)
void s0_k(const float* __restrict__ q0f, const __half* __restrict__ K16,
          float* __restrict__ s0f, int b0, float aQK)
{
    const int z = blockIdx.x;
    const int b = b0 + z;
    const int s = blockIdx.y * 256 + threadIdx.x;
    const int t = threadIdx.x;
    __shared__ float qrow[768];
    qrow[t] = q0f[b * 768 + t];
    qrow[t + 256] = q0f[b * 768 + t + 256];
    qrow[t + 512] = q0f[b * 768 + t + 512];
    __syncthreads();
    const __half* kr = K16 + (long long)z * SD + (long long)s * 768;
    float acc = 0.f;
    for (int k = 0; k < 768; ++k) acc += qrow[k] * (float)kr[k];
    s0f[b * 1024 + s] = acc * aQK;
}

__global__ __launch_bounds__(256)
void sm0_k(float* __restrict__ s0f, int b0)
{
    float* p = s0f + (long long)(b0 + blockIdx.x) * 1024;
    const int t = threadIdx.x;
    float v[4];
    float mx = -1e30f;
    #pragma unroll
    for (int j = 0; j < 4; ++j) { v[j] = p[t + 256 * j]; mx = fmaxf(mx, v[j]); }
    __shared__ float red[256];
    red[t] = mx; __syncthreads();
    for (int s = 128; s > 0; s >>= 1) { if (t < s) red[t] = fmaxf(red[t], red[t + s]); __syncthreads(); }
    mx = red[0];
    __syncthreads();
    float sum = 0.f;
    #pragma unroll
    for (int j = 0; j < 4; ++j) { v[j] = __expf(v[j] - mx); sum += v[j]; }
    red[t] = sum; __syncthreads();
    for (int s = 128; s > 0; s >>= 1) { if (t < s) red[t] += red[t + s]; __syncthreads(); }
    const float inv = 1.0f / red[0];
    __syncthreads();
    #pragma unroll
    for (int j = 0; j < 4; ++j) p[t + 256 * j] = v[j] * inv;
}

__global__ __launch_bounds__(256)
void o0_k(const float* __restrict__ p0f, const __half* __restrict__ Vt16,
          float* __restrict__ o0f, int b0, float invSig)
{
    const int z = blockIdx.x;
    const int b = b0 + z;
    const int d = blockIdx.y * 256 + threadIdx.x;
    const int t = threadIdx.x;
    __shared__ float prow[1024];
    #pragma unroll
    for (int j = 0; j < 4; ++j) prow[t + 256 * j] = p0f[b * 1024 + t + 256 * j];
    __syncthreads();
    const __half* vr = Vt16 + (long long)z * SD + (long long)d * 1024;
    float acc = 0.f;
    for (int s = 0; s < 1024; ++s) acc += prow[s] * (float)vr[s];
    o0f[b * 768 + d] = acc * invSig;
}

__global__ __launch_bounds__(256)
void headf_k(const float* __restrict__ o0f, const float* __restrict__ Wh,
             const float* __restrict__ bh, float* __restrict__ out)
{
    const int b = blockIdx.x;
    const int t = threadIdx.x;
    float s = 0.f;
    for (int d = t; d < 768; d += 256) s += o0f[b * 768 + d] * Wh[d];
    __shared__ float red[256];
    red[t] = s; __syncthreads();
    for (int k = 128; k > 0; k >>= 1) { if (t < k) red[t] += red[t + k]; __syncthreads(); }
    if (t == 0) out[b] = red[0] + bh[0];
}

// ---------------------------------------------------------------------------
extern "C" void kernel_launch(void* const* d_in, const int* in_sizes, int n_in,
                              void* d_out, int out_size, void* d_ws, size_t ws_size,
                              hipStream_t stream)
{
    const float* hs = (const float*)d_in[0];
    const float* Wq = (const float*)d_in[1];
    const float* bq = (const float*)d_in[2];
    const float* Wk = (const float*)d_in[3];
    const float* bk = (const float*)d_in[4];
    const float* Wv = (const float*)d_in[5];
    const float* bv = (const float*)d_in[6];
    const float* lk = (const float*)d_in[7];
    const float* lv = (const float*)d_in[8];
    const float* Wh = (const float*)d_in[9];
    const float* bh = (const float*)d_in[10];
    float* outp = (float*)d_out;

    // ---- workspace layout ----
    __half* H16  = (__half*)d_ws;                    // 32*SD halves
    __half* Wcat = H16 + (long long)B_ * SD;         // 12*LDL halves
    float*  bsb  = (float*)(Wcat + 12LL * LDL);      // 12*2304
    float*  bss  = bsb + 12 * 2304;
    float*  q0f  = bss + 12 * 2304;                  // 32*768
    float*  s0f  = q0f + 32 * 768;                   // 32*1024
    float*  o0f  = s0f + 32 * 1024;                  // 32*768
    float*  rsp  = o0f + 32 * 768;                   // 32*1024*8 partial rowsums
    float*  inv  = rsp + 32LL * 8192;                // 32*1024
    __half* Q16  = (__half*)(inv + 32 * 1024);

    const size_t baseBytes = (size_t)((char*)Q16 - (char*)d_ws);
    const size_t perG = ((size_t)(3 * SD) + (size_t)SS) * 2;   // ~6.8 MB
    long long avail = (long long)ws_size - (long long)baseBytes;
    int G = (avail > 0) ? (int)(avail / perG) : 1;
    if (G >= 32) G = 32; else if (G >= 16) G = 16; else if (G >= 8) G = 8;
    if (G < 1) G = 1;
    __half* K16  = Q16 + (long long)G * SD;
    __half* Vt16 = K16 + (long long)G * SD;
    __half* P16  = Vt16 + (long long)G * SD;

    // ---- converts ----
    cvt32to16_k<<<dim3((int)((B_ * SD) / 1024)), 256, 0, stream>>>(hs, H16);
    wtrans_k<<<dim3(12, 12, 12), 256, 0, stream>>>(Wq, Wcat, LDL, 0);
    wtrans_k<<<dim3(12, 12, 12), 256, 0, stream>>>(Wk, Wcat, LDL, 768);
    wtrans_k<<<dim3(12, 12, 12), 256, 0, stream>>>(Wv, Wcat, LDL, 1536);
    bscat_k<<<dim3((L_ * 2304 + 255) / 256), 256, 0, stream>>>(bq, bk, bv, lk, lv, bsb, bss);

    const float scq = 0.036084391824351615f;   // 1/sqrt(768)
    float sig = 1.f;

    // ---- layers 1..11 (full) ----
    for (int lyr = 0; lyr < L_ - 1; ++lyr) {
        const __half* W = Wcat + (long long)lyr * LDL;
        const float* bb = bsb + lyr * 2304;
        const float* ss = bss + lyr * 2304;
        const float aQK = scq / (sig * sig);

        for (int b0 = 0; b0 < B_; b0 += G) {
            const int nb = (B_ - b0 < G) ? (B_ - b0) : G;
            const __half* hg = H16 + (long long)b0 * SD;

            // fused QKV projection, m-slab swizzled (mPerXcd = nb m-tiles/XCD)
            gemm_qkv_k<<<dim3(18 * 8 * nb), 256, 0, stream>>>(
                hg, W, bb, ss, sig, Q16, K16, Vt16, 0, 18, nb);

            if ((nb & 7) == 0) {
                gemm_att_k<1, 1><<<dim3(nb * 64), 256, 0, stream>>>(
                    Q16, K16, aQK, P16, 768, 1024, SD, SD, SS, 8, 64, nb >> 3, rsp, nullptr);
            } else {
                gemm_att_k<0, 1><<<dim3(8, 8, nb), 256, 0, stream>>>(
                    Q16, K16, aQK, P16, 768, 1024, SD, SD, SS, 8, 64, 1, rsp, nullptr);
            }

            rowsuminv_k<<<dim3(nb * 4), 256, 0, stream>>>(rsp, inv, nb * 1024);

            if ((nb & 7) == 0) {
                gemm_att_k<1, 2><<<dim3(nb * 48), 256, 0, stream>>>(
                    P16, Vt16, 4.f, H16 + (long long)b0 * SD, 1024, 768, SS, SD, SD,
                    6, 48, nb >> 3, nullptr, inv);
            } else {
                gemm_att_k<0, 2><<<dim3(6, 8, nb), 256, 0, stream>>>(
                    P16, Vt16, 4.f, H16 + (long long)b0 * SD, 1024, 768, SS, SD, SD,
                    6, 48, 1, nullptr, inv);
            }
        }
        sig *= 4.f;
    }

    // ---- layer 12: only row 0 of the output is needed ----
    const float aQK = scq / (sig * sig);
    q0_k<<<dim3(B_, 3), 256, 0, stream>>>(H16, Wcat, bq, q0f, sig);

    for (int b0 = 0; b0 < B_; b0 += G) {
        const int nb = (B_ - b0 < G) ? (B_ - b0) : G;
        const __half* hg = H16 + (long long)b0 * SD;

        // K,V projection only (cat rows 768..2303), region split at 768
        gemm_qkv_k<<<dim3(12 * 8 * nb), 256, 0, stream>>>(
            hg, Wcat + 11LL * LDL + 768LL * 768, bsb + 11 * 2304, bss + 11 * 2304,
            sig, K16 /*unused*/, K16, Vt16, 768, 12, nb);

        s0_k<<<dim3(nb, 4), 256, 0, stream>>>(q0f, K16, s0f, b0, aQK);
        sm0_k<<<dim3(nb), 256, 0, stream>>>(s0f, b0);
        o0_k<<<dim3(nb, 3), 256, 0, stream>>>(s0f, Vt16, o0f, b0, 1.f / sig);
    }

    headf_k<<<dim3(B_), 256, 0, stream>>>(o0f, Wh, bh, outp);
}

// Round 4
// 3482.231 us; speedup vs baseline: 1.0993x; 1.0404x over previous
//
#include <hip/hip_runtime.h>
#include <hip/hip_fp16.h>
#include <math.h>

#define B_ 32
#define S_ 1024
#define D_ 768
#define L_ 12
#define SD 786432LL      // S_*D_ halves per batch
#define SS 1048576LL     // S_*S_ halves per batch
#define DD 589824LL      // D_*D_
#define LDL 1769472LL    // 3*DD halves per layer of Wcat (2304 x 768)

typedef _Float16 half8 __attribute__((ext_vector_type(8)));
typedef float f32x4 __attribute__((ext_vector_type(4)));
typedef unsigned short u16;

// chunk swizzle for the epilogue LDS bounce (8-fp16 chunks within a 64-wide row)
#define SW(lr) ((((lr) ^ ((lr) >> 3)) & 7))

// global_load_lds, width 16
#define GLD16(p, o) __builtin_amdgcn_global_load_lds( \
        (const __attribute__((address_space(1))) void*)(p), \
        (__attribute__((address_space(3))) void*)&smem[o], 16, 0, 0)

// ---------------------------------------------------------------------------
// Shared K-loop shape (both GEMMs): 128x128 tile, 4 waves, BK=32 slices,
// 3-slot LDS ring (A slots @ s*4096, B slots @ 12288 + s*4096 u16; 48 KB).
// Depth-2 prefetch, counted gate. Per slice s:
//   [s_waitcnt vmcnt(4); s_barrier]   <- fused: retire slice s (all waves),
//                                        certify WAR on slot (s-1)%3
//   stage slice s+2 -> slot (s+2)%3   (4 x global_load_lds, skip at tail)
//   ds_read 8 x b128 (conflict-free swizzle) ; 16 MFMA
//   sched_barrier(0)                  <- pin MFMA+lgkm above next gate
// Last slice gates vmcnt(0). 48 KB/block -> 3 blocks/CU: independent blocks
// cover each other's residual latency (m114 mechanism) on top of the ring.
// ---------------------------------------------------------------------------

// ===========================================================================
// Fused QKV projection: C_cat = A(M x 768) . Wcat(2304 x 768)^T,
// epilogue region-split Q/K/Vt. XCD m-slab mapping keeps per-XCD set =
// rolling A m-tile (384 KB) + Wcat (3.4 MB) inside 4 MB L2.
// ===========================================================================
__global__ __launch_bounds__(256, 3)
void gemm_qkv_k(const __half* __restrict__ A, const __half* __restrict__ Wt,
                const float* __restrict__ biasC, const float* __restrict__ scaleC,
                float aBias,
                __half* __restrict__ CQ, __half* __restrict__ CK, __half* __restrict__ CVt,
                int nBase, int tilesX, int mPerXcd)
{
    __shared__ __align__(16) u16 smem[24576];   // 48 KB: ring 3x(4K A + 4K B)
    const int K = 768;

    const int flat = blockIdx.x;
    const int xcd = flat & 7;
    const int jj = flat >> 3;
    const int mLocal = jj / tilesX;
    const int nxI = jj - mLocal * tilesX;
    const int n0 = nxI * 128;
    const int m0 = (xcd * mPerXcd + mLocal) * 128;

    const int t = threadIdx.x;
    const int l = t & 63, w = t >> 6;
    const int wm = (w & 1) * 64, wn = (w >> 1) * 64;

    // staging: thread covers chunks u0 = t, u1 = t+256 of a 128x32 slice.
    // LDS linear in u; GLOBAL k-chunk pre-swizzled (m173 pattern).
    const int u0 = t, u1 = t + 256;
    const int r0 = u0 >> 2, c0 = (u0 & 3) ^ ((r0 >> 1) & 3);
    const int r1 = u1 >> 2, c1 = (u1 & 3) ^ ((r1 >> 1) & 3);
    const __half* gA0 = A + (long long)(m0 + r0) * K + c0 * 8;
    const __half* gA1 = A + (long long)(m0 + r1) * K + c1 * 8;
    const __half* gB0 = Wt + (long long)(n0 + r0) * K + c0 * 8;
    const __half* gB1 = Wt + (long long)(n0 + r1) * K + c1 * 8;

    int aoff[4], boff[4];
    const int kc = l >> 4;
    #pragma unroll
    for (int mt = 0; mt < 4; ++mt) {
        int rr = wm + mt * 16 + (l & 15);
        aoff[mt] = (rr * 4 + (kc ^ ((rr >> 1) & 3))) * 8;
        int rb = wn + mt * 16 + (l & 15);
        boff[mt] = (rb * 4 + (kc ^ ((rb >> 1) & 3))) * 8;
    }

    f32x4 acc[4][4];
    #pragma unroll
    for (int i = 0; i < 4; ++i)
        #pragma unroll
        for (int j = 0; j < 4; ++j)
            acc[i][j] = (f32x4){0.f, 0.f, 0.f, 0.f};

    // prologue: slice 0 -> slot 0, slice 1 -> slot 1 (8 loads in flight)
    GLD16(gA0,      u0 * 8);                 GLD16(gA1,      u1 * 8);
    GLD16(gB0,      12288 + u0 * 8);         GLD16(gB1,      12288 + u1 * 8);
    GLD16(gA0 + 32, 4096 + u0 * 8);          GLD16(gA1 + 32, 4096 + u1 * 8);
    GLD16(gB0 + 32, 12288 + 4096 + u0 * 8);  GLD16(gB1 + 32, 12288 + 4096 + u1 * 8);

    int cur = 0;
    #pragma unroll 3
    for (int k0 = 0; k0 < K; k0 += 32) {
        // fused counted gate: retire slice s everywhere, then cross barrier.
        if (k0 + 32 < K) asm volatile("s_waitcnt vmcnt(4)\n\ts_barrier" ::: "memory");
        else             asm volatile("s_waitcnt vmcnt(0)\n\ts_barrier" ::: "memory");
        // stage slice s+2 into slot (s+2)%3 (WAR-safe: readers of that slot
        // finished during slice s-1, certified by the barrier above)
        if (k0 + 64 < K) {
            const int ts = (cur + 2 >= 3) ? (cur - 1) : (cur + 2);
            const int tsa = ts * 4096, tsb = 12288 + ts * 4096;
            GLD16(gA0 + k0 + 64, tsa + u0 * 8);  GLD16(gA1 + k0 + 64, tsa + u1 * 8);
            GLD16(gB0 + k0 + 64, tsb + u0 * 8);  GLD16(gB1 + k0 + 64, tsb + u1 * 8);
        }
        const int sa = cur * 4096, sb = 12288 + cur * 4096;
        half8 af[4], bf[4];
        #pragma unroll
        for (int mt = 0; mt < 4; ++mt) af[mt] = *(const half8*)(const void*)&smem[sa + aoff[mt]];
        #pragma unroll
        for (int nt = 0; nt < 4; ++nt) bf[nt] = *(const half8*)(const void*)&smem[sb + boff[nt]];
        #pragma unroll
        for (int nt = 0; nt < 4; ++nt)
            #pragma unroll
            for (int mt = 0; mt < 4; ++mt)
                acc[mt][nt] = __builtin_amdgcn_mfma_f32_16x16x32_f16(af[mt], bf[nt], acc[mt][nt], 0, 0, 0);
        __builtin_amdgcn_sched_barrier(0);   // keep MFMA+lgkm above next gate
        cur = (cur >= 2) ? 0 : (cur + 1);
    }
    __syncthreads();   // ring reads done everywhere; smem reused for C bounce

    const int nCat0 = n0 + nBase;
    const int region = nCat0 / 768;
    const int colBase = nCat0 - region * 768;

    float badd[4], bmul[4];
    #pragma unroll
    for (int nt = 0; nt < 4; ++nt) {
        int gn = nCat0 + wn + nt * 16 + (l & 15);
        badd[nt] = aBias * biasC[gn];
        bmul[nt] = scaleC[gn];
    }

    const int qbase = w * 4096;
    #pragma unroll
    for (int mt = 0; mt < 4; ++mt) {
        #pragma unroll
        for (int nt = 0; nt < 4; ++nt) {
            #pragma unroll
            for (int i = 0; i < 4; ++i) {
                int lrow = mt * 16 + ((l >> 4) << 2) + i;
                int lcol = nt * 16 + (l & 15);
                float v = (acc[mt][nt][i] + badd[nt]) * bmul[nt];
                int cc = lcol >> 3, c7 = lcol & 7;
                smem[qbase + lrow * 64 + ((cc ^ SW(lrow)) << 3) + c7] =
                    __half_as_ushort(__float2half(v));
            }
        }
    }
    __syncthreads();

    if (region < 2) {
        __half* Creg = region ? CK : CQ;
        #pragma unroll
        for (int p = 0; p < 8; ++p) {
            int u = t + p * 256;
            int R = u >> 4, cc = u & 15;
            int qb = ((R >> 6) + ((cc >> 3) << 1)) * 4096;
            int lr = R & 63, lcc = cc & 7;
            half8 val = *(const half8*)(const void*)&smem[qb + lr * 64 + ((lcc ^ SW(lr)) << 3)];
            *(half8*)(void*)&Creg[(long long)(m0 + R) * 768 + colBase + cc * 8] = val;
        }
    } else {
        #pragma unroll
        for (int p = 0; p < 8; ++p) {
            int u = t + p * 256;
            int Crow = u >> 4, mcc = u & 15;
            __align__(16) u16 tmp[8];
            #pragma unroll
            for (int j = 0; j < 8; ++j) {
                int m = mcc * 8 + j;
                int qb = ((m >> 6) + ((Crow >> 6) << 1)) * 4096;
                int lr = m & 63, lcol = Crow & 63;
                int lcc = lcol >> 3;
                tmp[j] = smem[qb + lr * 64 + ((lcc ^ SW(lr)) << 3) + (lcol & 7)];
            }
            long long b = m0 >> 10;
            __half* dst = CVt + b * SD + (long long)(colBase + Crow) * 1024 + (m0 & 1023) + mcc * 8;
            *(half8*)(void*)dst = *(const half8*)(const void*)tmp;
        }
    }
}

// ===========================================================================
// Attention GEMM: C = f(A[1024 x K] . B[N x K]^T), per-batch. Same 3-slot
// ring K-loop (K = 768 or 1024, runtime). sums[] overlaid into ring region
// (offset 16384 u16) so LDS stays 48 KB -> 3 blocks/CU.
// MODE 1 (QK^T): v = exp(acc*aAcc) + partial rowsums (no-max softmax).
// MODE 2 (PV):   v = acc * aAcc * invsum[row].
// ===========================================================================
template<int SWIZ, int MODE>
__global__ __launch_bounds__(256, 3)
void gemm_att_k(const __half* __restrict__ A, const __half* __restrict__ B,
                float aAcc, __half* __restrict__ C, int K, int ldc,
                long long sA, long long sB, long long sC,
                int tilesX, int tilesPB, int bpx,
                float* __restrict__ rsp, const float* __restrict__ invsum)
{
    __shared__ __align__(16) u16 smem[24576];   // 48 KB ring; epilogue reuse
    float* sums = (float*)(void*)&smem[16384];  // 8.5 KB, disjoint from qbase

    int nxI, ny;
    long long bz;
    if (SWIZ) {
        int flat = blockIdx.x;
        int xcd = flat & 7;
        int j = flat >> 3;
        int bLocal = j / tilesPB;
        int tt = j - bLocal * tilesPB;
        bz = (long long)(xcd * bpx + bLocal);
        ny = tt / tilesX;
        nxI = tt - ny * tilesX;
    } else {
        nxI = blockIdx.x; ny = blockIdx.y; bz = blockIdx.z;
    }

    const int t = threadIdx.x;
    const int l = t & 63, w = t >> 6;
    const int n0 = nxI * 128;
    const int m0 = ny * 128;
    A += bz * sA; B += bz * sB; C += bz * sC;

    const int wm = (w & 1) * 64, wn = (w >> 1) * 64;

    const int u0 = t, u1 = t + 256;
    const int r0 = u0 >> 2, c0 = (u0 & 3) ^ ((r0 >> 1) & 3);
    const int r1 = u1 >> 2, c1 = (u1 & 3) ^ ((r1 >> 1) & 3);
    const __half* gA0 = A + (long long)(m0 + r0) * K + c0 * 8;
    const __half* gA1 = A + (long long)(m0 + r1) * K + c1 * 8;
    const __half* gB0 = B + (long long)(n0 + r0) * K + c0 * 8;
    const __half* gB1 = B + (long long)(n0 + r1) * K + c1 * 8;

    int aoff[4], boff[4];
    const int kc = l >> 4;
    #pragma unroll
    for (int mt = 0; mt < 4; ++mt) {
        int rr = wm + mt * 16 + (l & 15);
        aoff[mt] = (rr * 4 + (kc ^ ((rr >> 1) & 3))) * 8;
        int rb = wn + mt * 16 + (l & 15);
        boff[mt] = (rb * 4 + (kc ^ ((rb >> 1) & 3))) * 8;
    }

    f32x4 acc[4][4];
    #pragma unroll
    for (int i = 0; i < 4; ++i)
        #pragma unroll
        for (int j = 0; j < 4; ++j)
            acc[i][j] = (f32x4){0.f, 0.f, 0.f, 0.f};

    // prologue: slice 0 -> slot 0, slice 1 -> slot 1
    GLD16(gA0,      u0 * 8);                 GLD16(gA1,      u1 * 8);
    GLD16(gB0,      12288 + u0 * 8);         GLD16(gB1,      12288 + u1 * 8);
    GLD16(gA0 + 32, 4096 + u0 * 8);          GLD16(gA1 + 32, 4096 + u1 * 8);
    GLD16(gB0 + 32, 12288 + 4096 + u0 * 8);  GLD16(gB1 + 32, 12288 + 4096 + u1 * 8);

    int cur = 0;
    #pragma unroll 3
    for (int k0 = 0; k0 < K; k0 += 32) {
        if (k0 + 32 < K) asm volatile("s_waitcnt vmcnt(4)\n\ts_barrier" ::: "memory");
        else             asm volatile("s_waitcnt vmcnt(0)\n\ts_barrier" ::: "memory");
        if (k0 + 64 < K) {
            const int ts = (cur + 2 >= 3) ? (cur - 1) : (cur + 2);
            const int tsa = ts * 4096, tsb = 12288 + ts * 4096;
            GLD16(gA0 + k0 + 64, tsa + u0 * 8);  GLD16(gA1 + k0 + 64, tsa + u1 * 8);
            GLD16(gB0 + k0 + 64, tsb + u0 * 8);  GLD16(gB1 + k0 + 64, tsb + u1 * 8);
        }
        const int sa = cur * 4096, sb = 12288 + cur * 4096;
        half8 af[4], bf[4];
        #pragma unroll
        for (int mt = 0; mt < 4; ++mt) af[mt] = *(const half8*)(const void*)&smem[sa + aoff[mt]];
        #pragma unroll
        for (int nt = 0; nt < 4; ++nt) bf[nt] = *(const half8*)(const void*)&smem[sb + boff[nt]];
        #pragma unroll
        for (int nt = 0; nt < 4; ++nt)
            #pragma unroll
            for (int mt = 0; mt < 4; ++mt)
                acc[mt][nt] = __builtin_amdgcn_mfma_f32_16x16x32_f16(af[mt], bf[nt], acc[mt][nt], 0, 0, 0);
        __builtin_amdgcn_sched_barrier(0);
        cur = (cur >= 2) ? 0 : (cur + 1);
    }
    __syncthreads();   // ring dead; smem reused for epilogue bounce

    // per-thread 1/rowsum values for MODE 2 (broadcast loads, L2-hot)
    float invr[4][4];
    if (MODE == 2) {
        #pragma unroll
        for (int mt = 0; mt < 4; ++mt)
            #pragma unroll
            for (int i = 0; i < 4; ++i)
                invr[mt][i] = invsum[bz * 1024 + m0 + wm + mt * 16 + ((l >> 4) << 2) + i];
    }

    const int qbase = w * 4096;
    #pragma unroll
    for (int mt = 0; mt < 4; ++mt) {
        #pragma unroll
        for (int nt = 0; nt < 4; ++nt) {
            #pragma unroll
            for (int i = 0; i < 4; ++i) {
                int lrow = mt * 16 + ((l >> 4) << 2) + i;
                int lcol = nt * 16 + (l & 15);
                float v;
                if (MODE == 1)      v = __expf(acc[mt][nt][i] * aAcc);
                else                v = acc[mt][nt][i] * aAcc * invr[mt][i];
                int cc = lcol >> 3, c7 = lcol & 7;
                smem[qbase + lrow * 64 + ((cc ^ SW(lrow)) << 3) + c7] =
                    __half_as_ushort(__float2half(v));
            }
        }
    }
    __syncthreads();

    #pragma unroll
    for (int p = 0; p < 8; ++p) {
        int u = t + p * 256;
        int R = u >> 4, cc = u & 15;
        int qb = ((R >> 6) + ((cc >> 3) << 1)) * 4096;
        int lr = R & 63, lcc = cc & 7;
        half8 val = *(const half8*)(const void*)&smem[qb + lr * 64 + ((lcc ^ SW(lr)) << 3)];
        *(half8*)(void*)&C[(long long)(m0 + R) * ldc + n0 + cc * 8] = val;
        if (MODE == 1) {
            float s8 = 0.f;
            #pragma unroll
            for (int j = 0; j < 8; ++j) s8 += (float)val[j];
            sums[R * 17 + cc] = s8;
        }
    }
    if (MODE == 1) {
        __syncthreads();
        if (t < 128) {
            float s = 0.f;
            #pragma unroll
            for (int c = 0; c < 16; ++c) s += sums[t * 17 + c];
            rsp[bz * 8192 + (long long)(m0 + t) * 8 + nxI] = s;
        }
    }
}

// inv[i] = 1 / sum_{c<8} rsp[i*8+c]
__global__ __launch_bounds__(256)
void rowsuminv_k(const float* __restrict__ rsp, float* __restrict__ inv, int n)
{
    int i = blockIdx.x * 256 + threadIdx.x;
    if (i < n) {
        const float* p = rsp + (long long)i * 8;
        float s = ((p[0] + p[1]) + (p[2] + p[3])) + ((p[4] + p[5]) + (p[6] + p[7]));
        inv[i] = 1.0f / s;
    }
}

// ---------------------------------------------------------------------------
__global__ __launch_bounds__(256)
void cvt32to16_k(const float* __restrict__ X, __half* __restrict__ Y)
{
    long long i = ((long long)blockIdx.x * 256 + threadIdx.x) * 4;
    float4 v = *(const float4*)&X[i];
    *(__half2*)&Y[i]     = __floats2half2_rn(v.x, v.y);
    *(__half2*)&Y[i + 2] = __floats2half2_rn(v.z, v.w);
}

// W[l][k][n] fp32 -> Wcat[l][rowOff + n][k] fp16
__global__ __launch_bounds__(256)
void wtrans_k(const float* __restrict__ W, __half* __restrict__ Wt,
              long long ldL, int rowOff)
{
    __shared__ float Ls[64][65];
    const int lyr = blockIdx.z;
    const int k0 = blockIdx.y * 64, n0 = blockIdx.x * 64;
    const float* src = W + (long long)lyr * DD;
    __half* dst = Wt + (long long)lyr * ldL;
    const int t = threadIdx.x;
    #pragma unroll
    for (int p = 0; p < 4; ++p) {
        int u = t + p * 256;
        int r = u >> 4, c4 = (u & 15) * 4;
        float4 v = *(const float4*)&src[(long long)(k0 + r) * D_ + n0 + c4];
        Ls[r][c4] = v.x; Ls[r][c4 + 1] = v.y; Ls[r][c4 + 2] = v.z; Ls[r][c4 + 3] = v.w;
    }
    __syncthreads();
    #pragma unroll
    for (int p = 0; p < 2; ++p) {
        int u = t + p * 256;
        int n = u >> 3, kc8 = (u & 7) * 8;
        __align__(16) u16 tmp[8];
        #pragma unroll
        for (int j = 0; j < 8; ++j) {
            _Float16 h = (_Float16)Ls[kc8 + j][n];
            tmp[j] = *(const u16*)&h;
        }
        *(half8*)(void*)&dst[(long long)(rowOff + n0 + n) * D_ + k0 + kc8] =
            *(const half8*)(const void*)tmp;
    }
}

// build concatenated bias/scale: [l][2304]: Q: (bq, 1) K: (bk, lk) V: (bv, lv)
__global__ __launch_bounds__(256)
void bscat_k(const float* __restrict__ bq, const float* __restrict__ bk,
             const float* __restrict__ bv, const float* __restrict__ lk,
             const float* __restrict__ lv, float* __restrict__ bsb,
             float* __restrict__ bss)
{
    int i = blockIdx.x * 256 + threadIdx.x;
    if (i >= L_ * 2304) return;
    int l = i / 2304, p = i - l * 2304;
    int r = p / 768, c = p - r * 768;
    float b, s;
    if (r == 0)      { b = bq[l * 768 + c]; s = 1.f; }
    else if (r == 1) { b = bk[l * 768 + c]; s = lk[l * 768 + c]; }
    else             { b = bv[l * 768 + c]; s = lv[l * 768 + c]; }
    bsb[i] = b; bss[i] = s;
}

// ---------------- layer-12 row-0 shortcut (fp32) ----------------
__global__ __launch_bounds__(256)
void q0_k(const __half* __restrict__ H16, const __half* __restrict__ Wcat,
          const float* __restrict__ bq, float* __restrict__ q0f, float sig)
{
    const int b = blockIdx.x;
    const int n = blockIdx.y * 256 + threadIdx.x;
    const int t = threadIdx.x;
    __shared__ __half hrow[768];
    const __half* h = H16 + (long long)b * SD;
    hrow[t] = h[t]; hrow[t + 256] = h[t + 256]; hrow[t + 512] = h[t + 512];
    __syncthreads();
    const __half* wr = Wcat + 11LL * LDL + (long long)n * 768;
    float acc = 0.f;
    for (int k = 0; k < 768; ++k) acc += (float)hrow[k] * (float)wr[k];
    q0f[b * 768 + n] = acc + sig * bq[11 * 768 + n];
}

__global__ __launch_bounds__(256)
void s0_k(const float* __restrict__ q0f, const __half* __restrict__ K16,
          float* __restrict__ s0f, int b0, float aQK)
{
    const int z = blockIdx.x;
    const int b = b0 + z;
    const int s = blockIdx.y * 256 + threadIdx.x;
    const int t = threadIdx.x;
    __shared__ float qrow[768];
    qrow[t] = q0f[b * 768 + t];
    qrow[t + 256] = q0f[b * 768 + t + 256];
    qrow[t + 512] = q0f[b * 768 + t + 512];
    __syncthreads();
    const __half* kr = K16 + (long long)z * SD + (long long)s * 768;
    float acc = 0.f;
    for (int k = 0; k < 768; ++k) acc += qrow[k] * (float)kr[k];
    s0f[b * 1024 + s] = acc * aQK;
}

__global__ __launch_bounds__(256)
void sm0_k(float* __restrict__ s0f, int b0)
{
    float* p = s0f + (long long)(b0 + blockIdx.x) * 1024;
    const int t = threadIdx.x;
    float v[4];
    float mx = -1e30f;
    #pragma unroll
    for (int j = 0; j < 4; ++j) { v[j] = p[t + 256 * j]; mx = fmaxf(mx, v[j]); }
    __shared__ float red[256];
    red[t] = mx; __syncthreads();
    for (int s = 128; s > 0; s >>= 1) { if (t < s) red[t] = fmaxf(red[t], red[t + s]); __syncthreads(); }
    mx = red[0];
    __syncthreads();
    float sum = 0.f;
    #pragma unroll
    for (int j = 0; j < 4; ++j) { v[j] = __expf(v[j] - mx); sum += v[j]; }
    red[t] = sum; __syncthreads();
    for (int s = 128; s > 0; s >>= 1) { if (t < s) red[t] += red[t + s]; __syncthreads(); }
    const float inv = 1.0f / red[0];
    __syncthreads();
    #pragma unroll
    for (int j = 0; j < 4; ++j) p[t + 256 * j] = v[j] * inv;
}

__global__ __launch_bounds__(256)
void o0_k(const float* __restrict__ p0f, const __half* __restrict__ Vt16,
          float* __restrict__ o0f, int b0, float invSig)
{
    const int z = blockIdx.x;
    const int b = b0 + z;
    const int d = blockIdx.y * 256 + threadIdx.x;
    const int t = threadIdx.x;
    __shared__ float prow[1024];
    #pragma unroll
    for (int j = 0; j < 4; ++j) prow[t + 256 * j] = p0f[b * 1024 + t + 256 * j];
    __syncthreads();
    const __half* vr = Vt16 + (long long)z * SD + (long long)d * 1024;
    float acc = 0.f;
    for (int s = 0; s < 1024; ++s) acc += prow[s] * (float)vr[s];
    o0f[b * 768 + d] = acc * invSig;
}

__global__ __launch_bounds__(256)
void headf_k(const float* __restrict__ o0f, const float* __restrict__ Wh,
             const float* __restrict__ bh, float* __restrict__ out)
{
    const int b = blockIdx.x;
    const int t = threadIdx.x;
    float s = 0.f;
    for (int d = t; d < 768; d += 256) s += o0f[b * 768 + d] * Wh[d];
    __shared__ float red[256];
    red[t] = s; __syncthreads();
    for (int k = 128; k > 0; k >>= 1) { if (t < k) red[t] += red[t + k]; __syncthreads(); }
    if (t == 0) out[b] = red[0] + bh[0];
}

// ---------------------------------------------------------------------------
extern "C" void kernel_launch(void* const* d_in, const int* in_sizes, int n_in,
                              void* d_out, int out_size, void* d_ws, size_t ws_size,
                              hipStream_t stream)
{
    const float* hs = (const float*)d_in[0];
    const float* Wq = (const float*)d_in[1];
    const float* bq = (const float*)d_in[2];
    const float* Wk = (const float*)d_in[3];
    const float* bk = (const float*)d_in[4];
    const float* Wv = (const float*)d_in[5];
    const float* bv = (const float*)d_in[6];
    const float* lk = (const float*)d_in[7];
    const float* lv = (const float*)d_in[8];
    const float* Wh = (const float*)d_in[9];
    const float* bh = (const float*)d_in[10];
    float* outp = (float*)d_out;

    // ---- workspace layout ----
    __half* H16  = (__half*)d_ws;                    // 32*SD halves
    __half* Wcat = H16 + (long long)B_ * SD;         // 12*LDL halves
    float*  bsb  = (float*)(Wcat + 12LL * LDL);      // 12*2304
    float*  bss  = bsb + 12 * 2304;
    float*  q0f  = bss + 12 * 2304;                  // 32*768
    float*  s0f  = q0f + 32 * 768;                   // 32*1024
    float*  o0f  = s0f + 32 * 1024;                  // 32*768
    float*  rsp  = o0f + 32 * 768;                   // 32*1024*8 partial rowsums
    float*  inv  = rsp + 32LL * 8192;                // 32*1024
    __half* Q16  = (__half*)(inv + 32 * 1024);

    const size_t baseBytes = (size_t)((char*)Q16 - (char*)d_ws);
    const size_t perG = ((size_t)(3 * SD) + (size_t)SS) * 2;   // ~6.8 MB
    long long avail = (long long)ws_size - (long long)baseBytes;
    int G = (avail > 0) ? (int)(avail / perG) : 1;
    if (G >= 32) G = 32; else if (G >= 16) G = 16; else if (G >= 8) G = 8;
    if (G < 1) G = 1;
    __half* K16  = Q16 + (long long)G * SD;
    __half* Vt16 = K16 + (long long)G * SD;
    __half* P16  = Vt16 + (long long)G * SD;

    // ---- converts ----
    cvt32to16_k<<<dim3((int)((B_ * SD) / 1024)), 256, 0, stream>>>(hs, H16);
    wtrans_k<<<dim3(12, 12, 12), 256, 0, stream>>>(Wq, Wcat, LDL, 0);
    wtrans_k<<<dim3(12, 12, 12), 256, 0, stream>>>(Wk, Wcat, LDL, 768);
    wtrans_k<<<dim3(12, 12, 12), 256, 0, stream>>>(Wv, Wcat, LDL, 1536);
    bscat_k<<<dim3((L_ * 2304 + 255) / 256), 256, 0, stream>>>(bq, bk, bv, lk, lv, bsb, bss);

    const float scq = 0.036084391824351615f;   // 1/sqrt(768)
    float sig = 1.f;

    // ---- layers 1..11 (full) ----
    for (int lyr = 0; lyr < L_ - 1; ++lyr) {
        const __half* W = Wcat + (long long)lyr * LDL;
        const float* bb = bsb + lyr * 2304;
        const float* ss = bss + lyr * 2304;
        const float aQK = scq / (sig * sig);

        for (int b0 = 0; b0 < B_; b0 += G) {
            const int nb = (B_ - b0 < G) ? (B_ - b0) : G;
            const __half* hg = H16 + (long long)b0 * SD;

            // fused QKV projection, m-slab swizzled (mPerXcd = nb m-tiles/XCD)
            gemm_qkv_k<<<dim3(18 * 8 * nb), 256, 0, stream>>>(
                hg, W, bb, ss, sig, Q16, K16, Vt16, 0, 18, nb);

            if ((nb & 7) == 0) {
                gemm_att_k<1, 1><<<dim3(nb * 64), 256, 0, stream>>>(
                    Q16, K16, aQK, P16, 768, 1024, SD, SD, SS, 8, 64, nb >> 3, rsp, nullptr);
            } else {
                gemm_att_k<0, 1><<<dim3(8, 8, nb), 256, 0, stream>>>(
                    Q16, K16, aQK, P16, 768, 1024, SD, SD, SS, 8, 64, 1, rsp, nullptr);
            }

            rowsuminv_k<<<dim3(nb * 4), 256, 0, stream>>>(rsp, inv, nb * 1024);

            if ((nb & 7) == 0) {
                gemm_att_k<1, 2><<<dim3(nb * 48), 256, 0, stream>>>(
                    P16, Vt16, 4.f, H16 + (long long)b0 * SD, 1024, 768, SS, SD, SD,
                    6, 48, nb >> 3, nullptr, inv);
            } else {
                gemm_att_k<0, 2><<<dim3(6, 8, nb), 256, 0, stream>>>(
                    P16, Vt16, 4.f, H16 + (long long)b0 * SD, 1024, 768, SS, SD, SD,
                    6, 48, 1, nullptr, inv);
            }
        }
        sig *= 4.f;
    }

    // ---- layer 12: only row 0 of the output is needed ----
    const float aQK = scq / (sig * sig);
    q0_k<<<dim3(B_, 3), 256, 0, stream>>>(H16, Wcat, bq, q0f, sig);

    for (int b0 = 0; b0 < B_; b0 += G) {
        const int nb = (B_ - b0 < G) ? (B_ - b0) : G;
        const __half* hg = H16 + (long long)b0 * SD;

        // K,V projection only (cat rows 768..2303), region split at 768
        gemm_qkv_k<<<dim3(12 * 8 * nb), 256, 0, stream>>>(
            hg, Wcat + 11LL * LDL + 768LL * 768, bsb + 11 * 2304, bss + 11 * 2304,
            sig, K16 /*unused*/, K16, Vt16, 768, 12, nb);

        s0_k<<<dim3(nb, 4), 256, 0, stream>>>(q0f, K16, s0f, b0, aQK);
        sm0_k<<<dim3(nb), 256, 0, stream>>>(s0f, b0);
        o0_k<<<dim3(nb, 3), 256, 0, stream>>>(s0f, Vt16, o0f, b0, 1.f / sig);
    }

    headf_k<<<dim3(B_), 256, 0, stream>>>(o0f, Wh, bh, outp);
}